// Round 14
// baseline (51.039 us; speedup 1.0000x reference)
//
#include <hip/hip_runtime.h>
#include <hip/hip_fp16.h>

#define B_   8
#define LQ_  128
#define LK_  1024
#define H_   128

// tanh(q+k) = 1 - 2/(EQ*EK + 1), EQ=exp(2q') f32, EK=exp(2k') stored f16
// TRANSPOSED [b][h][s] packed as half2: score loads coalesced (wave=256B).
// f16 EK: k'~N(0,1); saturation (|k'|>5.5) -> tanh -> +/-1 (correct limit);
// rel err 2^-11 -> score err ~2e-4 (absmax 1.95e-3 measured in R13, thr 8.3e-3).
__device__ float        g_eq  [B_ * LQ_ * H_];
__device__ unsigned int g_ekT2[B_ * H_ * (LK_ / 2)];   // half2-packed

#define C2LOG2E 2.8853900817779268f      // 2/ln2

// Tiled projection, column-split: grid (288, 2), 48KB LDS. (R13-proven)
__global__ __launch_bounds__(256) void proj_kernel(const float* __restrict__ q,
                                                   const float* __restrict__ k,
                                                   const float* __restrict__ Wq,
                                                   const float* __restrict__ Wk) {
    __shared__ float Ws[H_ * 64];
    __shared__ float Xs[32 * H_];
    const int t = threadIdx.x;
    const int tile = blockIdx.x;
    const int ch = blockIdx.y;
    const bool isq = (tile < 32);
    const float* X; const float* W; int r0;
    if (isq) { X = q; W = Wq; r0 = tile * 32; }
    else     { X = k; W = Wk; r0 = (tile - 32) * 32; }

    #pragma unroll
    for (int u = 0; u < 8; ++u) {
        int p = u * 256 + t;
        int kk = p >> 4, c4 = p & 15;
        *(float4*)(Ws + kk * 64 + c4 * 4) = *(const float4*)(W + kk * H_ + ch * 64 + c4 * 4);
    }
    #pragma unroll
    for (int u = 0; u < 4; ++u) {
        int idx = u * 256 + t;
        int r = idx >> 5, c = idx & 31;
        *(float4*)(Xs + r * H_ + c * 4) = *(const float4*)(X + (size_t)(r0 + r) * H_ + c * 4);
    }
    __syncthreads();

    const int r4 = t >> 5;
    const int tc = t & 31;
    float acc[4][2] = {};
    #pragma unroll 4
    for (int kk = 0; kk < H_; ++kk) {
        float2 w2 = *(const float2*)(Ws + kk * 64 + tc * 2);
        #pragma unroll
        for (int i = 0; i < 4; ++i) {
            float x = Xs[(r4 * 4 + i) * H_ + kk];
            acc[i][0] = fmaf(x, w2.x, acc[i][0]);
            acc[i][1] = fmaf(x, w2.y, acc[i][1]);
        }
    }
    if (isq) {
        #pragma unroll
        for (int i = 0; i < 4; ++i) {
            float2 o;
            o.x = __builtin_amdgcn_exp2f(acc[i][0] * C2LOG2E);
            o.y = __builtin_amdgcn_exp2f(acc[i][1] * C2LOG2E);
            *(float2*)(g_eq + (size_t)(r0 + r4 * 4 + i) * H_ + ch * 64 + tc * 2) = o;
        }
    } else {
        const int b = r0 >> 10;
        const int sb = (r0 & 1023) + r4 * 4;
        #pragma unroll
        for (int j = 0; j < 2; ++j) {
            const int h = ch * 64 + tc * 2 + j;
            float e0 = __builtin_amdgcn_exp2f(acc[0][j] * C2LOG2E);
            float e1 = __builtin_amdgcn_exp2f(acc[1][j] * C2LOG2E);
            float e2 = __builtin_amdgcn_exp2f(acc[2][j] * C2LOG2E);
            float e3 = __builtin_amdgcn_exp2f(acc[3][j] * C2LOG2E);
            __half2 p0 = __floats2half2_rn(e0, e1);
            __half2 p1 = __floats2half2_rn(e2, e3);
            uint2 pk = make_uint2(*(unsigned int*)&p0, *(unsigned int*)&p1);
            *(uint2*)(g_ekT2 + (size_t)(b * H_ + h) * (LK_ / 2) + (sb >> 1)) = pk;
        }
    }
}

// Fused scores + masked softmax + PV, 4 q-rows per block (256 x 512).
// Phase 1: thread owns s in {2t,2t+1}, feeds 4 rows (8 acc streams): one
// half2 EK load serves 16 products; q/w reads block-uniform (scalar).
// Phase 2: 128 threads per row (2 waves), shfl + LDS combine.
// Phase 3: one float2 values load feeds 4 rows (8 fma); LDS partials.
// All phases barrier-fenced, branches block-uniform -> race-free.
__global__ __launch_bounds__(512) void fused_attn(const float* __restrict__ values,
                                                  const int* __restrict__ valid_lens,
                                                  const float* __restrict__ w_v,
                                                  float* __restrict__ out) {
    __shared__ float sc[4][LK_];         // 16 KB
    __shared__ float red[8], sred[8];
    __shared__ float rinvs[4];
    __shared__ float part[8][4][H_];     // 16 KB
    const int t = threadIdx.x;
    const int b = blockIdx.x >> 5, l0 = (blockIdx.x & 31) * 4;
    int valid = valid_lens[b];
    valid = min(max(valid, 0), LK_);

    // ---- Phase 1: scores for s < valid ----
    const int s0 = 2 * t;                // 0..1022
    if (s0 < valid) {
        const float* __restrict__ qr = g_eq + (size_t)(b * LQ_ + l0) * H_;
        const unsigned int* __restrict__ ek = g_ekT2 + (size_t)b * H_ * (LK_ / 2) + t;
        float a[4][2] = {};
        float wsum = 0.0f;
        #pragma unroll 2
        for (int h = 0; h < H_; ++h) {
            unsigned int u = ek[(size_t)h * (LK_ / 2)];
            float2 ef = __half22float2(*(const __half2*)&u);
            const float wh = w_v[h];
            wsum += wh;
            #pragma unroll
            for (int r = 0; r < 4; ++r) {
                const float qh = qr[r * H_ + h];
                a[r][0] = fmaf(wh, __builtin_amdgcn_rcpf(fmaf(qh, ef.x, 1.0f)), a[r][0]);
                a[r][1] = fmaf(wh, __builtin_amdgcn_rcpf(fmaf(qh, ef.y, 1.0f)), a[r][1]);
            }
        }
        #pragma unroll
        for (int r = 0; r < 4; ++r)
            *(float2*)(&sc[r][s0]) = make_float2(fmaf(-2.0f, a[r][0], wsum),
                                                 fmaf(-2.0f, a[r][1], wsum));
    }
    __syncthreads();

    // ---- Phase 2: masked softmax per row (weights in sc, 1/sum in rinvs) ----
    int n;
    if (valid == 0) {                    // ref: all -1e6 -> uniform
        n = LK_;
        for (int i = t; i < 4 * LK_; i += 512) sc[i >> 10][i & 1023] = 1.0f;
        if (t < 4) rinvs[t] = 1.0f / 1024.0f;
    } else {
        n = valid;
        const int r = t >> 7;            // row [0,4)
        const int tt = t & 127;          // 128 threads per row
        const int wid = (t >> 6) & 1;    // wave-half within row
        float* srow = sc[r];
        float m = -3.0e38f;
        for (int i = tt; i < n; i += 128) m = fmaxf(m, srow[i]);
        #pragma unroll
        for (int kk = 32; kk; kk >>= 1) m = fmaxf(m, __shfl_xor(m, kk, 64));
        if ((tt & 63) == 0) red[r * 2 + wid] = m;
        __syncthreads();
        m = fmaxf(red[r * 2], red[r * 2 + 1]);
        float ps = 0.0f;
        for (int i = tt; i < n; i += 128) {
            float e = __builtin_amdgcn_exp2f((srow[i] - m) * 1.44269504f);
            srow[i] = e;
            ps += e;
        }
        #pragma unroll
        for (int kk = 32; kk; kk >>= 1) ps += __shfl_xor(ps, kk, 64);
        if ((tt & 63) == 0) sred[r * 2 + wid] = ps;
        __syncthreads();
        if (t < 4) rinvs[t] = 1.0f / (sred[t * 2] + sred[t * 2 + 1]);
    }
    __syncthreads();

    // ---- Phase 3: PV. One float2 values load feeds 4 rows; 8-way s-split ----
    const int c = t >> 6;                // s-chunk [0,8)
    const int v2 = t & 63;
    const float* vb = values + (size_t)b * LK_ * H_ + 2 * v2;
    float ax[4] = {}, ay[4] = {};
    #pragma unroll 4
    for (int s = c; s < n; s += 8) {
        float2 vv = *(const float2*)(vb + (size_t)s * H_);
        #pragma unroll
        for (int r = 0; r < 4; ++r) {
            float w = sc[r][s];
            ax[r] = fmaf(w, vv.x, ax[r]);
            ay[r] = fmaf(w, vv.y, ay[r]);
        }
    }
    #pragma unroll
    for (int r = 0; r < 4; ++r)
        *(float2*)(&part[c][r][2 * v2]) = make_float2(ax[r], ay[r]);
    __syncthreads();
    {
        const int rr = t >> 7, v = t & 127;      // 4 rows x 128 v = 512
        float o = (((part[0][rr][v] + part[1][rr][v]) + (part[2][rr][v] + part[3][rr][v]))
                 + ((part[4][rr][v] + part[5][rr][v]) + (part[6][rr][v] + part[7][rr][v])));
        out[(b * LQ_ + l0 + rr) * H_ + v] = o * rinvs[rr];
    }
}

extern "C" void kernel_launch(void* const* d_in, const int* in_sizes, int n_in,
                              void* d_out, int out_size, void* d_ws, size_t ws_size,
                              hipStream_t stream) {
    const float* queries    = (const float*)d_in[0];
    const float* keys       = (const float*)d_in[1];
    const float* values     = (const float*)d_in[2];
    const int*   valid_lens = (const int*)d_in[3];
    const float* W_q        = (const float*)d_in[4];
    const float* W_k        = (const float*)d_in[5];
    const float* w_v        = (const float*)d_in[6];
    float* out = (float*)d_out;
    (void)d_ws; (void)ws_size; (void)in_sizes; (void)n_in; (void)out_size;

    proj_kernel<<<dim3(288, 2), 256, 0, stream>>>(queries, keys, W_q, W_k);
    fused_attn <<<256, 512, 0, stream>>>(values, valid_lens, w_v, out);
}

// Round 15
// 45.676 us; speedup vs baseline: 1.1174x; 1.1174x over previous
//
#include <hip/hip_runtime.h>
#include <hip/hip_fp16.h>

#define B_   8
#define LQ_  128
#define LK_  1024
#define H_   128

// tanh(q+k) = 1 - 2/(EQ*EK + 1), EQ=exp(2q') f32, EK=exp(2k') f16 in [b][h][s]
// (half2-packed -> coalesced score loads). values also pre-packed to f16
// ([b][s][v] half2 pairs along v). f16 rel err 2^-11; measured absmax 1.95e-3
// (R13) + ~1e-3 from f16 values, threshold 8.3e-3.
__device__ float        g_eq  [B_ * LQ_ * H_];
__device__ unsigned int g_ekT2[B_ * H_ * (LK_ / 2)];
__device__ unsigned int g_vh  [B_ * LK_ * (H_ / 2)];

#define C2LOG2E 2.8853900817779268f      // 2/ln2

// Tiled projection, column-split: grid (288, 2), 48KB LDS. (R13-proven)
__global__ __launch_bounds__(256) void proj_kernel(const float* __restrict__ q,
                                                   const float* __restrict__ k,
                                                   const float* __restrict__ Wq,
                                                   const float* __restrict__ Wk) {
    __shared__ float Ws[H_ * 64];
    __shared__ float Xs[32 * H_];
    const int t = threadIdx.x;
    const int tile = blockIdx.x;
    const int ch = blockIdx.y;
    const bool isq = (tile < 32);
    const float* X; const float* W; int r0;
    if (isq) { X = q; W = Wq; r0 = tile * 32; }
    else     { X = k; W = Wk; r0 = (tile - 32) * 32; }

    #pragma unroll
    for (int u = 0; u < 8; ++u) {
        int p = u * 256 + t;
        int kk = p >> 4, c4 = p & 15;
        *(float4*)(Ws + kk * 64 + c4 * 4) = *(const float4*)(W + kk * H_ + ch * 64 + c4 * 4);
    }
    #pragma unroll
    for (int u = 0; u < 4; ++u) {
        int idx = u * 256 + t;
        int r = idx >> 5, c = idx & 31;
        *(float4*)(Xs + r * H_ + c * 4) = *(const float4*)(X + (size_t)(r0 + r) * H_ + c * 4);
    }
    __syncthreads();

    const int r4 = t >> 5;
    const int tc = t & 31;
    float acc[4][2] = {};
    #pragma unroll 4
    for (int kk = 0; kk < H_; ++kk) {
        float2 w2 = *(const float2*)(Ws + kk * 64 + tc * 2);
        #pragma unroll
        for (int i = 0; i < 4; ++i) {
            float x = Xs[(r4 * 4 + i) * H_ + kk];
            acc[i][0] = fmaf(x, w2.x, acc[i][0]);
            acc[i][1] = fmaf(x, w2.y, acc[i][1]);
        }
    }
    if (isq) {
        #pragma unroll
        for (int i = 0; i < 4; ++i) {
            float2 o;
            o.x = __builtin_amdgcn_exp2f(acc[i][0] * C2LOG2E);
            o.y = __builtin_amdgcn_exp2f(acc[i][1] * C2LOG2E);
            *(float2*)(g_eq + (size_t)(r0 + r4 * 4 + i) * H_ + ch * 64 + tc * 2) = o;
        }
    } else {
        const int b = r0 >> 10;
        const int sb = (r0 & 1023) + r4 * 4;
        #pragma unroll
        for (int j = 0; j < 2; ++j) {
            const int h = ch * 64 + tc * 2 + j;
            float e0 = __builtin_amdgcn_exp2f(acc[0][j] * C2LOG2E);
            float e1 = __builtin_amdgcn_exp2f(acc[1][j] * C2LOG2E);
            float e2 = __builtin_amdgcn_exp2f(acc[2][j] * C2LOG2E);
            float e3 = __builtin_amdgcn_exp2f(acc[3][j] * C2LOG2E);
            __half2 p0 = __floats2half2_rn(e0, e1);
            __half2 p1 = __floats2half2_rn(e2, e3);
            uint2 pk = make_uint2(*(unsigned int*)&p0, *(unsigned int*)&p1);
            *(uint2*)(g_ekT2 + (size_t)(b * H_ + h) * (LK_ / 2) + (sb >> 1)) = pk;
        }
    }
}

// values f32 -> f16 pack: thread converts one float4 (4 v) -> uint2.
// 262144 threads = 1024 blocks x 256. Coalesced 16B loads / 8B stores.
__global__ __launch_bounds__(256) void conv_values(const float* __restrict__ values) {
    const int idx = blockIdx.x * 256 + threadIdx.x;     // [0, B*LK*32)
    float4 v = *(const float4*)(values + (size_t)idx * 4);
    __half2 p0 = __floats2half2_rn(v.x, v.y);
    __half2 p1 = __floats2half2_rn(v.z, v.w);
    *(uint2*)(g_vh + (size_t)idx * 2) = make_uint2(*(unsigned int*)&p0, *(unsigned int*)&p1);
}

// Fused scores + masked softmax + PV, 2 q-rows per block (512 x 512).
// Phase 1: thread owns s in {2t,2t+1}; 4-deep explicit EK prefetch pipeline;
// q/w reads block-uniform (scalar path). Phase 2/3: R13-proven patterns,
// PV reads f16 values (uint/lane, coalesced). All phases barrier-fenced.
__global__ __launch_bounds__(512) void fused_attn(const int* __restrict__ valid_lens,
                                                  const float* __restrict__ w_v,
                                                  float* __restrict__ out) {
    __shared__ float sA[LK_], sB[LK_];
    __shared__ float red[8], sred[16];
    __shared__ float rinvs[2];
    __shared__ float part[8][2][H_];
    const int t = threadIdx.x;
    const int b = blockIdx.x >> 6, l0 = (blockIdx.x & 63) * 2;
    int valid = valid_lens[b];
    valid = min(max(valid, 0), LK_);

    // ---- Phase 1: scores for s < valid ----
    const int s0 = 2 * t;
    if (s0 < valid) {
        const float* __restrict__ q0 = g_eq + (size_t)(b * LQ_ + l0) * H_;
        const float* __restrict__ q1 = q0 + H_;
        const unsigned int* __restrict__ ek = g_ekT2 + (size_t)b * H_ * (LK_ / 2) + t;
        float a00 = 0.0f, a01 = 0.0f, a10 = 0.0f, a11 = 0.0f, wsum = 0.0f;
        unsigned int pf0 = ek[0 * (LK_ / 2)];
        unsigned int pf1 = ek[1 * (LK_ / 2)];
        unsigned int pf2 = ek[2 * (LK_ / 2)];
        unsigned int pf3 = ek[3 * (LK_ / 2)];
        for (int h0 = 0; h0 < H_; h0 += 4) {
            const unsigned int c0 = pf0, c1 = pf1, c2 = pf2, c3 = pf3;
            if (h0 + 8 <= H_) {
                pf0 = ek[(size_t)(h0 + 4) * (LK_ / 2)];
                pf1 = ek[(size_t)(h0 + 5) * (LK_ / 2)];
                pf2 = ek[(size_t)(h0 + 6) * (LK_ / 2)];
                pf3 = ek[(size_t)(h0 + 7) * (LK_ / 2)];
            }
            #pragma unroll
            for (int i = 0; i < 4; ++i) {
                const unsigned int u = (i == 0) ? c0 : (i == 1) ? c1 : (i == 2) ? c2 : c3;
                float2 ef = __half22float2(*(const __half2*)&u);
                const int h = h0 + i;
                const float qa = q0[h], qb = q1[h], wh = w_v[h];
                wsum += wh;
                a00 = fmaf(wh, __builtin_amdgcn_rcpf(fmaf(qa, ef.x, 1.0f)), a00);
                a01 = fmaf(wh, __builtin_amdgcn_rcpf(fmaf(qa, ef.y, 1.0f)), a01);
                a10 = fmaf(wh, __builtin_amdgcn_rcpf(fmaf(qb, ef.x, 1.0f)), a10);
                a11 = fmaf(wh, __builtin_amdgcn_rcpf(fmaf(qb, ef.y, 1.0f)), a11);
            }
        }
        *(float2*)(sA + s0) = make_float2(fmaf(-2.0f, a00, wsum), fmaf(-2.0f, a01, wsum));
        *(float2*)(sB + s0) = make_float2(fmaf(-2.0f, a10, wsum), fmaf(-2.0f, a11, wsum));
    }
    __syncthreads();

    // ---- Phase 2: masked softmax (weights in sA/sB, 1/sum in rinvs) ----
    int n;
    if (valid == 0) {                    // ref: all -1e6 -> uniform
        n = LK_;
        for (int i = t; i < LK_; i += 512) { sA[i] = 1.0f; sB[i] = 1.0f; }
        if (t == 0) { rinvs[0] = 1.0f / 1024.0f; rinvs[1] = 1.0f / 1024.0f; }
    } else {
        n = valid;
        const int r = t >> 8, tt = t & 255;      // 256 threads per row
        const int w4id = tt >> 6;
        float* srow = r ? sB : sA;
        float m = -3.0e38f;
        for (int i = tt; i < n; i += 256) m = fmaxf(m, srow[i]);
        #pragma unroll
        for (int kk = 32; kk; kk >>= 1) m = fmaxf(m, __shfl_xor(m, kk, 64));
        if ((tt & 63) == 0) red[r * 4 + w4id] = m;
        __syncthreads();
        m = fmaxf(fmaxf(red[r * 4], red[r * 4 + 1]), fmaxf(red[r * 4 + 2], red[r * 4 + 3]));
        float ps = 0.0f;
        for (int i = tt; i < n; i += 256) {
            float e = __builtin_amdgcn_exp2f((srow[i] - m) * 1.44269504f);
            srow[i] = e;
            ps += e;
        }
        #pragma unroll
        for (int kk = 32; kk; kk >>= 1) ps += __shfl_xor(ps, kk, 64);
        if ((tt & 63) == 0) sred[r * 4 + w4id] = ps;
        __syncthreads();
        if (t < 2) {
            float s4 = (sred[t * 4] + sred[t * 4 + 1]) + (sred[t * 4 + 2] + sred[t * 4 + 3]);
            rinvs[t] = 1.0f / s4;
        }
    }
    __syncthreads();

    // ---- Phase 3: PV with f16 values (1 uint = 2 v per lane), 8-way s-split ----
    const int c = t >> 6;
    const int v2 = t & 63;
    const unsigned int* vb = g_vh + (size_t)b * LK_ * (H_ / 2) + v2;
    float ax0 = 0.0f, ay0 = 0.0f, ax1 = 0.0f, ay1 = 0.0f;
    #pragma unroll 4
    for (int s = c; s < n; s += 8) {
        unsigned int u = vb[(size_t)s * (H_ / 2)];
        float2 vv = __half22float2(*(const __half2*)&u);
        float w0 = sA[s], w1 = sB[s];
        ax0 = fmaf(w0, vv.x, ax0); ay0 = fmaf(w0, vv.y, ay0);
        ax1 = fmaf(w1, vv.x, ax1); ay1 = fmaf(w1, vv.y, ay1);
    }
    *(float2*)(&part[c][0][2 * v2]) = make_float2(ax0, ay0);
    *(float2*)(&part[c][1][2 * v2]) = make_float2(ax1, ay1);
    __syncthreads();
    if (t < 256) {
        const int l = t >> 7, v = t & 127;
        float o = (((part[0][l][v] + part[1][l][v]) + (part[2][l][v] + part[3][l][v]))
                 + ((part[4][l][v] + part[5][l][v]) + (part[6][l][v] + part[7][l][v])));
        out[(b * LQ_ + l0 + l) * H_ + v] = o * rinvs[l];
    }
}

extern "C" void kernel_launch(void* const* d_in, const int* in_sizes, int n_in,
                              void* d_out, int out_size, void* d_ws, size_t ws_size,
                              hipStream_t stream) {
    const float* queries    = (const float*)d_in[0];
    const float* keys       = (const float*)d_in[1];
    const float* values     = (const float*)d_in[2];
    const int*   valid_lens = (const int*)d_in[3];
    const float* W_q        = (const float*)d_in[4];
    const float* W_k        = (const float*)d_in[5];
    const float* w_v        = (const float*)d_in[6];
    float* out = (float*)d_out;
    (void)d_ws; (void)ws_size; (void)in_sizes; (void)n_in; (void)out_size;

    proj_kernel<<<dim3(288, 2), 256, 0, stream>>>(queries, keys, W_q, W_k);
    conv_values<<<1024, 256, 0, stream>>>(values);
    fused_attn <<<512, 512, 0, stream>>>(valid_lens, w_v, out);
}

// Round 16
// 43.109 us; speedup vs baseline: 1.1840x; 1.0595x over previous
//
#include <hip/hip_runtime.h>
#include <hip/hip_fp16.h>

#define B_   8
#define LQ_  128
#define LK_  1024
#define H_   128

// tanh(q+k) = 1 - 2/(EQ*EK + 1), EQ=exp(2q') f32, EK=exp(2k') f16 in [b][h][s]
// (half2-packed -> coalesced score loads). values pre-packed f16 along v.
// f16 rel err 2^-11; measured absmax 1.95e-3 (R13/R15), threshold 8.3e-3.
__device__ float        g_eq  [B_ * LQ_ * H_];
__device__ unsigned int g_ekT2[B_ * H_ * (LK_ / 2)];
__device__ unsigned int g_vh  [B_ * LK_ * (H_ / 2)];

#define C2LOG2E 2.8853900817779268f      // 2/ln2

// Tiled projection, column-split: grid (288, 2), 48KB LDS. (R13-proven)
__global__ __launch_bounds__(256) void proj_kernel(const float* __restrict__ q,
                                                   const float* __restrict__ k,
                                                   const float* __restrict__ Wq,
                                                   const float* __restrict__ Wk) {
    __shared__ float Ws[H_ * 64];
    __shared__ float Xs[32 * H_];
    const int t = threadIdx.x;
    const int tile = blockIdx.x;
    const int ch = blockIdx.y;
    const bool isq = (tile < 32);
    const float* X; const float* W; int r0;
    if (isq) { X = q; W = Wq; r0 = tile * 32; }
    else     { X = k; W = Wk; r0 = (tile - 32) * 32; }

    #pragma unroll
    for (int u = 0; u < 8; ++u) {
        int p = u * 256 + t;
        int kk = p >> 4, c4 = p & 15;
        *(float4*)(Ws + kk * 64 + c4 * 4) = *(const float4*)(W + kk * H_ + ch * 64 + c4 * 4);
    }
    #pragma unroll
    for (int u = 0; u < 4; ++u) {
        int idx = u * 256 + t;
        int r = idx >> 5, c = idx & 31;
        *(float4*)(Xs + r * H_ + c * 4) = *(const float4*)(X + (size_t)(r0 + r) * H_ + c * 4);
    }
    __syncthreads();

    const int r4 = t >> 5;
    const int tc = t & 31;
    float acc[4][2] = {};
    #pragma unroll 4
    for (int kk = 0; kk < H_; ++kk) {
        float2 w2 = *(const float2*)(Ws + kk * 64 + tc * 2);
        #pragma unroll
        for (int i = 0; i < 4; ++i) {
            float x = Xs[(r4 * 4 + i) * H_ + kk];
            acc[i][0] = fmaf(x, w2.x, acc[i][0]);
            acc[i][1] = fmaf(x, w2.y, acc[i][1]);
        }
    }
    if (isq) {
        #pragma unroll
        for (int i = 0; i < 4; ++i) {
            float2 o;
            o.x = __builtin_amdgcn_exp2f(acc[i][0] * C2LOG2E);
            o.y = __builtin_amdgcn_exp2f(acc[i][1] * C2LOG2E);
            *(float2*)(g_eq + (size_t)(r0 + r4 * 4 + i) * H_ + ch * 64 + tc * 2) = o;
        }
    } else {
        const int b = r0 >> 10;
        const int sb = (r0 & 1023) + r4 * 4;
        #pragma unroll
        for (int j = 0; j < 2; ++j) {
            const int h = ch * 64 + tc * 2 + j;
            float e0 = __builtin_amdgcn_exp2f(acc[0][j] * C2LOG2E);
            float e1 = __builtin_amdgcn_exp2f(acc[1][j] * C2LOG2E);
            float e2 = __builtin_amdgcn_exp2f(acc[2][j] * C2LOG2E);
            float e3 = __builtin_amdgcn_exp2f(acc[3][j] * C2LOG2E);
            __half2 p0 = __floats2half2_rn(e0, e1);
            __half2 p1 = __floats2half2_rn(e2, e3);
            uint2 pk = make_uint2(*(unsigned int*)&p0, *(unsigned int*)&p1);
            *(uint2*)(g_ekT2 + (size_t)(b * H_ + h) * (LK_ / 2) + (sb >> 1)) = pk;
        }
    }
}

// values f32 -> f16 pack (R15-proven).
__global__ __launch_bounds__(256) void conv_values(const float* __restrict__ values) {
    const int idx = blockIdx.x * 256 + threadIdx.x;
    float4 v = *(const float4*)(values + (size_t)idx * 4);
    __half2 p0 = __floats2half2_rn(v.x, v.y);
    __half2 p1 = __floats2half2_rn(v.z, v.w);
    *(uint2*)(g_vh + (size_t)idx * 2) = make_uint2(*(unsigned int*)&p0, *(unsigned int*)&p1);
}

// Fused scores + masked softmax + PV, ONE row per block, 1024 blocks x 512
// threads -> 4 blocks/CU = 32 waves/CU (max occupancy; latency was the R13-R15
// binding constraint). CU holds 4 distinct b's -> valid imbalance averages out.
// Phase 1: thread owns s in {2t,2t+1}; one uint EK load per h (coalesced 256B/
// wave); q/w block-uniform scalar loads; compiler-scheduled unroll (R13 form).
// Phase 2/3: proven reduce patterns, 1-row shape. All barrier-fenced.
__global__ __launch_bounds__(512) void fused_attn(const int* __restrict__ valid_lens,
                                                  const float* __restrict__ w_v,
                                                  float* __restrict__ out) {
    __shared__ float sc[LK_];
    __shared__ float red[8], sred[8];
    __shared__ float rinv_s;
    __shared__ float part[8][H_];
    const int t = threadIdx.x;
    const int lane = t & 63, wid = t >> 6;
    const int b = blockIdx.x >> 7, l = blockIdx.x & 127;
    int valid = valid_lens[b];
    valid = min(max(valid, 0), LK_);

    // ---- Phase 1: scores for s < valid ----
    const int s0 = 2 * t;
    if (s0 < valid) {
        const float* __restrict__ q0 = g_eq + (size_t)(b * LQ_ + l) * H_;
        const unsigned int* __restrict__ ek = g_ekT2 + (size_t)b * H_ * (LK_ / 2) + t;
        float a0 = 0.0f, a1 = 0.0f, wsum = 0.0f;
        #pragma unroll 8
        for (int h = 0; h < H_; ++h) {
            unsigned int u = ek[(size_t)h * (LK_ / 2)];
            float2 ef = __half22float2(*(const __half2*)&u);
            const float qh = q0[h], wh = w_v[h];
            wsum += wh;
            a0 = fmaf(wh, __builtin_amdgcn_rcpf(fmaf(qh, ef.x, 1.0f)), a0);
            a1 = fmaf(wh, __builtin_amdgcn_rcpf(fmaf(qh, ef.y, 1.0f)), a1);
        }
        *(float2*)(sc + s0) = make_float2(fmaf(-2.0f, a0, wsum), fmaf(-2.0f, a1, wsum));
    }
    __syncthreads();

    // ---- Phase 2: masked softmax (weights in sc, 1/sum in rinv) ----
    int n;
    if (valid == 0) {                    // ref: all -1e6 -> uniform
        n = LK_;
        for (int i = t; i < LK_; i += 512) sc[i] = 1.0f;
        if (t == 0) rinv_s = 1.0f / 1024.0f;
    } else {
        n = valid;
        float m = -3.0e38f;
        for (int i = t; i < n; i += 512) m = fmaxf(m, sc[i]);
        #pragma unroll
        for (int kk = 32; kk; kk >>= 1) m = fmaxf(m, __shfl_xor(m, kk, 64));
        if (lane == 0) red[wid] = m;
        __syncthreads();
        m = fmaxf(fmaxf(fmaxf(red[0], red[1]), fmaxf(red[2], red[3])),
                  fmaxf(fmaxf(red[4], red[5]), fmaxf(red[6], red[7])));
        float ps = 0.0f;
        for (int i = t; i < n; i += 512) {
            float e = __builtin_amdgcn_exp2f((sc[i] - m) * 1.44269504f);
            sc[i] = e;
            ps += e;
        }
        #pragma unroll
        for (int kk = 32; kk; kk >>= 1) ps += __shfl_xor(ps, kk, 64);
        if (lane == 0) sred[wid] = ps;
        __syncthreads();
        if (t == 0) {
            float s8 = ((sred[0] + sred[1]) + (sred[2] + sred[3]))
                     + ((sred[4] + sred[5]) + (sred[6] + sred[7]));
            rinv_s = 1.0f / s8;
        }
    }
    __syncthreads();
    const float rinv = rinv_s;

    // ---- Phase 3: PV with f16 values (1 uint = 2 v per lane), 8-way s-split ----
    const int c = t >> 6;                // s-chunk [0,8)
    const int v2 = t & 63;
    const unsigned int* vb = g_vh + (size_t)b * LK_ * (H_ / 2) + v2;
    float ax = 0.0f, ay = 0.0f;
    #pragma unroll 4
    for (int s = c; s < n; s += 8) {
        unsigned int u = vb[(size_t)s * (H_ / 2)];
        float2 vv = __half22float2(*(const __half2*)&u);
        float w = sc[s];
        ax = fmaf(w, vv.x, ax);
        ay = fmaf(w, vv.y, ay);
    }
    *(float2*)(&part[c][2 * v2]) = make_float2(ax, ay);
    __syncthreads();
    if (t < H_) {
        float o = (((part[0][t] + part[1][t]) + (part[2][t] + part[3][t]))
                 + ((part[4][t] + part[5][t]) + (part[6][t] + part[7][t])));
        out[(b * LQ_ + l) * H_ + t] = o * rinv;
    }
}

extern "C" void kernel_launch(void* const* d_in, const int* in_sizes, int n_in,
                              void* d_out, int out_size, void* d_ws, size_t ws_size,
                              hipStream_t stream) {
    const float* queries    = (const float*)d_in[0];
    const float* keys       = (const float*)d_in[1];
    const float* values     = (const float*)d_in[2];
    const int*   valid_lens = (const int*)d_in[3];
    const float* W_q        = (const float*)d_in[4];
    const float* W_k        = (const float*)d_in[5];
    const float* w_v        = (const float*)d_in[6];
    float* out = (float*)d_out;
    (void)d_ws; (void)ws_size; (void)in_sizes; (void)n_in; (void)out_size;

    proj_kernel<<<dim3(288, 2), 256, 0, stream>>>(queries, keys, W_q, W_k);
    conv_values<<<1024, 256, 0, stream>>>(values);
    fused_attn <<<1024, 512, 0, stream>>>(valid_lens, w_v, out);
}

// Round 17
// 35.337 us; speedup vs baseline: 1.4444x; 1.2200x over previous
//
#include <hip/hip_runtime.h>
#include <hip/hip_fp16.h>

#define B_   8
#define LQ_  128
#define LK_  1024
#define H_   128

// tanh(q+k) = 1 - 2/(EQ*EK + 1), EQ=exp(2q') f32, EK=exp(2k') f16.
// g_ekT4[b][h4][sp] (uint4): uint j = half2( EK[4*h4+j][2*sp], EK[4*h4+j][2*sp+1] )
//   -> fused phase-1 load = 16B/lane, 4 h x 2 s per load, coalesced 1KB/wave.
// g_vh[b][s][v2] half2 along v (read as uint2 = 4 v). f16 rel err 2^-11;
// measured absmax 1.95e-3 (R13-R16), threshold 8.3e-3.
__device__ float        g_eq  [B_ * LQ_ * H_];
__device__ uint4        g_ekT4[B_ * (H_ / 4) * (LK_ / 2)];
__device__ unsigned int g_vh  [B_ * LK_ * (H_ / 2)];

#define C2LOG2E 2.8853900817779268f      // 2/ln2

// Merged projection + values-pack. Grid (800, 2) x 256:
//   x in [0,32):   queries @ Wq -> g_eq   (column half = y)
//   x in [32,288): keys    @ Wk -> g_ekT4 (f16, packed transpose)
//   x in [288,800): values f32 -> f16 pack (1024 virtual blocks via y)
// All branches block-uniform. Proj thread tile: 2 rows x 4 cols.
__global__ __launch_bounds__(256) void proj_conv(const float* __restrict__ q,
                                                 const float* __restrict__ k,
                                                 const float* __restrict__ Wq,
                                                 const float* __restrict__ Wk,
                                                 const float* __restrict__ values) {
    const int bx = blockIdx.x, ch = blockIdx.y;
    const int t = threadIdx.x;
    if (bx >= 288) {                     // ---- values pack ----
        const int idx = ((bx - 288) + (ch << 9)) * 256 + t;   // [0, 262144)
        float4 v = *(const float4*)(values + (size_t)idx * 4);
        __half2 p0 = __floats2half2_rn(v.x, v.y);
        __half2 p1 = __floats2half2_rn(v.z, v.w);
        *(uint2*)(g_vh + (size_t)idx * 2) =
            make_uint2(*(unsigned int*)&p0, *(unsigned int*)&p1);
        return;
    }
    __shared__ float Ws[H_ * 64];        // 32 KB: W cols [ch*64, ch*64+64)
    __shared__ float Xs[32 * H_];        // 16 KB
    const bool isq = (bx < 32);
    const float* X; const float* W; int r0;
    if (isq) { X = q; W = Wq; r0 = bx * 32; }
    else     { X = k; W = Wk; r0 = (bx - 32) * 32; }

    #pragma unroll
    for (int u = 0; u < 8; ++u) {
        int p = u * 256 + t;
        int kk = p >> 4, c4 = p & 15;
        *(float4*)(Ws + kk * 64 + c4 * 4) = *(const float4*)(W + kk * H_ + ch * 64 + c4 * 4);
    }
    #pragma unroll
    for (int u = 0; u < 4; ++u) {
        int idx = u * 256 + t;
        int r = idx >> 5, c = idx & 31;
        *(float4*)(Xs + r * H_ + c * 4) = *(const float4*)(X + (size_t)(r0 + r) * H_ + c * 4);
    }
    __syncthreads();

    const int rr = t >> 4;               // [0,16): 2 rows
    const int cc = t & 15;               // [0,16): 4 cols (within the 64 half)
    float acc[2][4] = {};
    #pragma unroll 4
    for (int kk = 0; kk < H_; ++kk) {
        float4 w4 = *(const float4*)(Ws + kk * 64 + cc * 4);
        float x0 = Xs[(rr * 2) * H_ + kk];
        float x1 = Xs[(rr * 2 + 1) * H_ + kk];
        acc[0][0] = fmaf(x0, w4.x, acc[0][0]); acc[0][1] = fmaf(x0, w4.y, acc[0][1]);
        acc[0][2] = fmaf(x0, w4.z, acc[0][2]); acc[0][3] = fmaf(x0, w4.w, acc[0][3]);
        acc[1][0] = fmaf(x1, w4.x, acc[1][0]); acc[1][1] = fmaf(x1, w4.y, acc[1][1]);
        acc[1][2] = fmaf(x1, w4.z, acc[1][2]); acc[1][3] = fmaf(x1, w4.w, acc[1][3]);
    }
    if (isq) {
        #pragma unroll
        for (int i = 0; i < 2; ++i) {
            float4 o;
            o.x = __builtin_amdgcn_exp2f(acc[i][0] * C2LOG2E);
            o.y = __builtin_amdgcn_exp2f(acc[i][1] * C2LOG2E);
            o.z = __builtin_amdgcn_exp2f(acc[i][2] * C2LOG2E);
            o.w = __builtin_amdgcn_exp2f(acc[i][3] * C2LOG2E);
            *(float4*)(g_eq + (size_t)(r0 + rr * 2 + i) * H_ + ch * 64 + cc * 4) = o;
        }
    } else {
        const int b  = r0 >> 10;         // 32-row tile never straddles b
        const int s0 = (r0 & 1023) + rr * 2;
        const int h4 = ch * 16 + cc;
        uint4 pk;
        #pragma unroll
        for (int j = 0; j < 4; ++j) {
            float e0 = __builtin_amdgcn_exp2f(acc[0][j] * C2LOG2E);   // s even
            float e1 = __builtin_amdgcn_exp2f(acc[1][j] * C2LOG2E);   // s odd
            __half2 p = __floats2half2_rn(e0, e1);
            ((unsigned int*)&pk)[j] = *(unsigned int*)&p;
        }
        g_ekT4[((size_t)b * (H_ / 4) + h4) * (LK_ / 2) + (s0 >> 1)] = pk;
    }
}

// Fused scores + masked softmax + PV, one row per block: 1024 x 512
// (4 blocks/CU = 32 waves/CU; CU mixes 4 b's -> valid imbalance averages).
// Phase 1: thread owns s in {2t,2t+1}; 32 uint4 loads (16B/lane) deliver
// 4h x 2s each; q/w block-uniform scalar loads. score = -2*sum (wsum dropped:
// softmax is shift-invariant). Phase 2: proven shfl+LDS softmax. Phase 3:
// PV uint2 loads (4 v/thread, 16-way s-split). All barrier-fenced.
__global__ __launch_bounds__(512, 8) void fused_attn(const int* __restrict__ valid_lens,
                                                     const float* __restrict__ w_v,
                                                     float* __restrict__ out) {
    __shared__ float sc[LK_];
    __shared__ float red[8], sred[8];
    __shared__ float rinv_s;
    __shared__ float part[16][H_];       // 8 KB
    const int t = threadIdx.x;
    const int lane = t & 63, wid = t >> 6;
    const int b = blockIdx.x >> 7, l = blockIdx.x & 127;
    int valid = valid_lens[b];
    valid = min(max(valid, 0), LK_);

    // ---- Phase 1: scores for s < valid ----
    const int s0 = 2 * t;
    if (s0 < valid) {
        const float* __restrict__ q0 = g_eq + (size_t)(b * LQ_ + l) * H_;
        const uint4* __restrict__ ek = g_ekT4 + (size_t)b * (H_ / 4) * (LK_ / 2) + t;
        float a0 = 0.0f, a1 = 0.0f;
        #pragma unroll 2
        for (int h4 = 0; h4 < H_ / 4; ++h4) {
            uint4 u = ek[(size_t)h4 * (LK_ / 2)];
            #pragma unroll
            for (int j = 0; j < 4; ++j) {
                unsigned int uj = ((const unsigned int*)&u)[j];
                float2 ef = __half22float2(*(const __half2*)&uj);
                const int h = h4 * 4 + j;
                const float qh = q0[h], wh = w_v[h];
                a0 = fmaf(wh, __builtin_amdgcn_rcpf(fmaf(qh, ef.x, 1.0f)), a0);
                a1 = fmaf(wh, __builtin_amdgcn_rcpf(fmaf(qh, ef.y, 1.0f)), a1);
            }
        }
        *(float2*)(sc + s0) = make_float2(-2.0f * a0, -2.0f * a1);
    }
    __syncthreads();

    // ---- Phase 2: masked softmax (weights in sc, 1/sum in rinv) ----
    int n;
    if (valid == 0) {                    // ref: all -1e6 -> uniform
        n = LK_;
        for (int i = t; i < LK_; i += 512) sc[i] = 1.0f;
        if (t == 0) rinv_s = 1.0f / 1024.0f;
    } else {
        n = valid;
        float m = -3.0e38f;
        for (int i = t; i < n; i += 512) m = fmaxf(m, sc[i]);
        #pragma unroll
        for (int kk = 32; kk; kk >>= 1) m = fmaxf(m, __shfl_xor(m, kk, 64));
        if (lane == 0) red[wid] = m;
        __syncthreads();
        m = fmaxf(fmaxf(fmaxf(red[0], red[1]), fmaxf(red[2], red[3])),
                  fmaxf(fmaxf(red[4], red[5]), fmaxf(red[6], red[7])));
        float ps = 0.0f;
        for (int i = t; i < n; i += 512) {
            float e = __builtin_amdgcn_exp2f((sc[i] - m) * 1.44269504f);
            sc[i] = e;
            ps += e;
        }
        #pragma unroll
        for (int kk = 32; kk; kk >>= 1) ps += __shfl_xor(ps, kk, 64);
        if (lane == 0) sred[wid] = ps;
        __syncthreads();
        if (t == 0) {
            float s8 = ((sred[0] + sred[1]) + (sred[2] + sred[3]))
                     + ((sred[4] + sred[5]) + (sred[6] + sred[7]));
            rinv_s = 1.0f / s8;
        }
    }
    __syncthreads();
    const float rinv = rinv_s;

    // ---- Phase 3: PV. uint2 = 4 v per lane; 16-way s-split ----
    const int c = t >> 5;                // s-chunk [0,16)
    const int v4 = t & 31;               // 4-v group
    const uint2* vb = (const uint2*)g_vh + (size_t)b * LK_ * (H_ / 4) + v4;
    float ax = 0.0f, ay = 0.0f, az = 0.0f, aw = 0.0f;
    #pragma unroll 4
    for (int s = c; s < n; s += 16) {
        uint2 u = vb[(size_t)s * (H_ / 4)];
        float2 v01 = __half22float2(*(const __half2*)&u.x);
        float2 v23 = __half22float2(*(const __half2*)&u.y);
        float w = sc[s];
        ax = fmaf(w, v01.x, ax); ay = fmaf(w, v01.y, ay);
        az = fmaf(w, v23.x, az); aw = fmaf(w, v23.y, aw);
    }
    *(float4*)(&part[c][4 * v4]) = make_float4(ax, ay, az, aw);
    __syncthreads();
    if (t < H_) {
        float o = 0.0f;
        #pragma unroll
        for (int cc2 = 0; cc2 < 16; ++cc2) o += part[cc2][t];
        out[(b * LQ_ + l) * H_ + t] = o * rinv;
    }
}

extern "C" void kernel_launch(void* const* d_in, const int* in_sizes, int n_in,
                              void* d_out, int out_size, void* d_ws, size_t ws_size,
                              hipStream_t stream) {
    const float* queries    = (const float*)d_in[0];
    const float* keys       = (const float*)d_in[1];
    const float* values     = (const float*)d_in[2];
    const int*   valid_lens = (const int*)d_in[3];
    const float* W_q        = (const float*)d_in[4];
    const float* W_k        = (const float*)d_in[5];
    const float* w_v        = (const float*)d_in[6];
    float* out = (float*)d_out;
    (void)d_ws; (void)ws_size; (void)in_sizes; (void)n_in; (void)out_size;

    proj_conv <<<dim3(800, 2), 256, 0, stream>>>(queries, keys, W_q, W_k, values);
    fused_attn<<<1024, 512, 0, stream>>>(valid_lens, w_v, out);
}

// Round 18
// 34.354 us; speedup vs baseline: 1.4857x; 1.0286x over previous
//
#include <hip/hip_runtime.h>
#include <hip/hip_fp16.h>

#define B_   8
#define LQ_  128
#define LK_  1024
#define H_   128

// tanh(q+k) = 1 - 2/(EQ*EK + 1), EQ=exp(2q') f32, EK=exp(2k') f16.
// g_ekT4[b][h4][sp] (uint4): uint j = half2( EK[4*h4+j][2*sp], EK[4*h4+j][2*sp+1] )
//   -> fused phase-1 load = 16B/lane, 4 h x 2 s per load, coalesced 1KB/wave.
// g_vh[b][s][v2] half2 along v (read as uint2 = 4 v). f16 rel err 2^-11;
// measured absmax 1.95e-3 (R13-R17), threshold 8.3e-3.
__device__ float        g_eq  [B_ * LQ_ * H_];
__device__ uint4        g_ekT4[B_ * (H_ / 4) * (LK_ / 2)];
__device__ unsigned int g_vh  [B_ * LK_ * (H_ / 2)];

#define C2LOG2E 2.8853900817779268f      // 2/ln2

// Merged projection + values-pack. (R17-proven, unchanged)
__global__ __launch_bounds__(256) void proj_conv(const float* __restrict__ q,
                                                 const float* __restrict__ k,
                                                 const float* __restrict__ Wq,
                                                 const float* __restrict__ Wk,
                                                 const float* __restrict__ values) {
    const int bx = blockIdx.x, ch = blockIdx.y;
    const int t = threadIdx.x;
    if (bx >= 288) {                     // ---- values pack ----
        const int idx = ((bx - 288) + (ch << 9)) * 256 + t;   // [0, 262144)
        float4 v = *(const float4*)(values + (size_t)idx * 4);
        __half2 p0 = __floats2half2_rn(v.x, v.y);
        __half2 p1 = __floats2half2_rn(v.z, v.w);
        *(uint2*)(g_vh + (size_t)idx * 2) =
            make_uint2(*(unsigned int*)&p0, *(unsigned int*)&p1);
        return;
    }
    __shared__ float Ws[H_ * 64];
    __shared__ float Xs[32 * H_];
    const bool isq = (bx < 32);
    const float* X; const float* W; int r0;
    if (isq) { X = q; W = Wq; r0 = bx * 32; }
    else     { X = k; W = Wk; r0 = (bx - 32) * 32; }

    #pragma unroll
    for (int u = 0; u < 8; ++u) {
        int p = u * 256 + t;
        int kk = p >> 4, c4 = p & 15;
        *(float4*)(Ws + kk * 64 + c4 * 4) = *(const float4*)(W + kk * H_ + ch * 64 + c4 * 4);
    }
    #pragma unroll
    for (int u = 0; u < 4; ++u) {
        int idx = u * 256 + t;
        int r = idx >> 5, c = idx & 31;
        *(float4*)(Xs + r * H_ + c * 4) = *(const float4*)(X + (size_t)(r0 + r) * H_ + c * 4);
    }
    __syncthreads();

    const int rr = t >> 4;               // [0,16): 2 rows
    const int cc = t & 15;               // [0,16): 4 cols
    float acc[2][4] = {};
    #pragma unroll 4
    for (int kk = 0; kk < H_; ++kk) {
        float4 w4 = *(const float4*)(Ws + kk * 64 + cc * 4);
        float x0 = Xs[(rr * 2) * H_ + kk];
        float x1 = Xs[(rr * 2 + 1) * H_ + kk];
        acc[0][0] = fmaf(x0, w4.x, acc[0][0]); acc[0][1] = fmaf(x0, w4.y, acc[0][1]);
        acc[0][2] = fmaf(x0, w4.z, acc[0][2]); acc[0][3] = fmaf(x0, w4.w, acc[0][3]);
        acc[1][0] = fmaf(x1, w4.x, acc[1][0]); acc[1][1] = fmaf(x1, w4.y, acc[1][1]);
        acc[1][2] = fmaf(x1, w4.z, acc[1][2]); acc[1][3] = fmaf(x1, w4.w, acc[1][3]);
    }
    if (isq) {
        #pragma unroll
        for (int i = 0; i < 2; ++i) {
            float4 o;
            o.x = __builtin_amdgcn_exp2f(acc[i][0] * C2LOG2E);
            o.y = __builtin_amdgcn_exp2f(acc[i][1] * C2LOG2E);
            o.z = __builtin_amdgcn_exp2f(acc[i][2] * C2LOG2E);
            o.w = __builtin_amdgcn_exp2f(acc[i][3] * C2LOG2E);
            *(float4*)(g_eq + (size_t)(r0 + rr * 2 + i) * H_ + ch * 64 + cc * 4) = o;
        }
    } else {
        const int b  = r0 >> 10;
        const int s0 = (r0 & 1023) + rr * 2;
        const int h4 = ch * 16 + cc;
        uint4 pk;
        #pragma unroll
        for (int j = 0; j < 4; ++j) {
            float e0 = __builtin_amdgcn_exp2f(acc[0][j] * C2LOG2E);   // s even
            float e1 = __builtin_amdgcn_exp2f(acc[1][j] * C2LOG2E);   // s odd
            __half2 p = __floats2half2_rn(e0, e1);
            ((unsigned int*)&pk)[j] = *(unsigned int*)&p;
        }
        g_ekT4[((size_t)b * (H_ / 4) + h4) * (LK_ / 2) + (s0 >> 1)] = pk;
    }
}

// Fused scores + softmax + PV, one row per block: 1024 x 512 (32 waves/CU).
// Phase 1 now folds the softmax exp: |score| <= 2*||w_v||_1 ~ 18 (rcp in (0,1)),
// far from f32 exp overflow (88), so max-subtraction is unnecessary. Each
// thread computes weights e = exp(score) in registers, writes sc, and
// accumulates a masked partial sum -> single shfl+LDS sum reduce (1 barrier).
// Deletes the max pass, the exp pass, and 2 barriers vs R17.
// Phase 3: PV uint2 loads (4 v/thread, 16-way s-split). Race-free by barriers.
__global__ __launch_bounds__(512, 8) void fused_attn(const int* __restrict__ valid_lens,
                                                     const float* __restrict__ w_v,
                                                     float* __restrict__ out) {
    __shared__ float sc[LK_];
    __shared__ float sred[8];
    __shared__ float rinv_s;
    __shared__ float part[16][H_];
    const int t = threadIdx.x;
    const int lane = t & 63, wid = t >> 6;
    const int b = blockIdx.x >> 7, l = blockIdx.x & 127;
    int valid = valid_lens[b];
    valid = min(max(valid, 0), LK_);

    // ---- Phase 1: scores -> weights (exp folded), masked partial sums ----
    const int s0 = 2 * t;
    float e0 = 0.0f, e1 = 0.0f;
    if (valid == 0) {
        for (int i = t; i < LK_; i += 512) sc[i] = 1.0f;
    } else if (s0 < valid) {
        const float* __restrict__ q0 = g_eq + (size_t)(b * LQ_ + l) * H_;
        const uint4* __restrict__ ek = g_ekT4 + (size_t)b * (H_ / 4) * (LK_ / 2) + t;
        float a0 = 0.0f, a1 = 0.0f;
        #pragma unroll 2
        for (int h4 = 0; h4 < H_ / 4; ++h4) {
            uint4 u = ek[(size_t)h4 * (LK_ / 2)];
            #pragma unroll
            for (int j = 0; j < 4; ++j) {
                unsigned int uj = ((const unsigned int*)&u)[j];
                float2 ef = __half22float2(*(const __half2*)&uj);
                const int h = h4 * 4 + j;
                const float qh = q0[h], wh = w_v[h];
                a0 = fmaf(wh, __builtin_amdgcn_rcpf(fmaf(qh, ef.x, 1.0f)), a0);
                a1 = fmaf(wh, __builtin_amdgcn_rcpf(fmaf(qh, ef.y, 1.0f)), a1);
            }
        }
        e0 = __builtin_amdgcn_exp2f(a0 * (-2.0f * 1.44269504f));
        float e1f = __builtin_amdgcn_exp2f(a1 * (-2.0f * 1.44269504f));
        *(float2*)(sc + s0) = make_float2(e0, e1f);
        e1 = (s0 + 1 < valid) ? e1f : 0.0f;
    }
    // ---- Phase 2: sum reduce over in-register weights ----
    float ps = e0 + e1;
    #pragma unroll
    for (int kk = 32; kk; kk >>= 1) ps += __shfl_xor(ps, kk, 64);
    if (lane == 0) sred[wid] = ps;
    __syncthreads();
    if (t == 0) {
        float s8 = ((sred[0] + sred[1]) + (sred[2] + sred[3]))
                 + ((sred[4] + sred[5]) + (sred[6] + sred[7]));
        rinv_s = (valid == 0) ? (1.0f / 1024.0f) : (1.0f / s8);
    }
    __syncthreads();
    const float rinv = rinv_s;
    const int n = (valid == 0) ? LK_ : valid;

    // ---- Phase 3: PV. uint2 = 4 v per lane; 16-way s-split ----
    const int c = t >> 5;                // s-chunk [0,16)
    const int v4 = t & 31;               // 4-v group
    const uint2* vb = (const uint2*)g_vh + (size_t)b * LK_ * (H_ / 4) + v4;
    float ax = 0.0f, ay = 0.0f, az = 0.0f, aw = 0.0f;
    #pragma unroll 4
    for (int s = c; s < n; s += 16) {
        uint2 u = vb[(size_t)s * (H_ / 4)];
        float2 v01 = __half22float2(*(const __half2*)&u.x);
        float2 v23 = __half22float2(*(const __half2*)&u.y);
        float w = sc[s];
        ax = fmaf(w, v01.x, ax); ay = fmaf(w, v01.y, ay);
        az = fmaf(w, v23.x, az); aw = fmaf(w, v23.y, aw);
    }
    *(float4*)(&part[c][4 * v4]) = make_float4(ax, ay, az, aw);
    __syncthreads();
    if (t < H_) {
        float o = 0.0f;
        #pragma unroll
        for (int cc2 = 0; cc2 < 16; ++cc2) o += part[cc2][t];
        out[(b * LQ_ + l) * H_ + t] = o * rinv;
    }
}

extern "C" void kernel_launch(void* const* d_in, const int* in_sizes, int n_in,
                              void* d_out, int out_size, void* d_ws, size_t ws_size,
                              hipStream_t stream) {
    const float* queries    = (const float*)d_in[0];
    const float* keys       = (const float*)d_in[1];
    const float* values     = (const float*)d_in[2];
    const int*   valid_lens = (const int*)d_in[3];
    const float* W_q        = (const float*)d_in[4];
    const float* W_k        = (const float*)d_in[5];
    const float* w_v        = (const float*)d_in[6];
    float* out = (float*)d_out;
    (void)d_ws; (void)ws_size; (void)in_sizes; (void)n_in; (void)out_size;

    proj_conv <<<dim3(800, 2), 256, 0, stream>>>(queries, keys, W_q, W_k, values);
    fused_attn<<<1024, 512, 0, stream>>>(valid_lens, w_v, out);
}

// Round 19
// 33.855 us; speedup vs baseline: 1.5076x; 1.0147x over previous
//
#include <hip/hip_runtime.h>
#include <hip/hip_fp16.h>

#define B_   8
#define LQ_  128
#define LK_  1024
#define H_   128

// tanh(q+k) = 1 - 2/(EQ*EK + 1), EQ=exp(2q') f32, EK=exp(2k') f16.
// g_ekT4[b][h4][sp] (uint4): uint j = half2( EK[4*h4+j][2*sp], EK[4*h4+j][2*sp+1] )
//   -> fused phase-1 load = 16B/lane, 4 h x 2 s per load, coalesced 1KB/wave.
// g_vh[b][s][v2] half2 along v (read as uint2 = 4 v). f16 rel err 2^-11;
// measured absmax 1.95e-3 (R13-R18), threshold 8.3e-3.
__device__ float        g_eq  [B_ * LQ_ * H_];
__device__ uint4        g_ekT4[B_ * (H_ / 4) * (LK_ / 2)];
__device__ unsigned int g_vh  [B_ * LK_ * (H_ / 2)];

#define C2LOG2E 2.8853900817779268f      // 2/ln2

// Merged projection + values-pack. (R17-proven, unchanged)
__global__ __launch_bounds__(256) void proj_conv(const float* __restrict__ q,
                                                 const float* __restrict__ k,
                                                 const float* __restrict__ Wq,
                                                 const float* __restrict__ Wk,
                                                 const float* __restrict__ values) {
    const int bx = blockIdx.x, ch = blockIdx.y;
    const int t = threadIdx.x;
    if (bx >= 288) {                     // ---- values pack ----
        const int idx = ((bx - 288) + (ch << 9)) * 256 + t;   // [0, 262144)
        float4 v = *(const float4*)(values + (size_t)idx * 4);
        __half2 p0 = __floats2half2_rn(v.x, v.y);
        __half2 p1 = __floats2half2_rn(v.z, v.w);
        *(uint2*)(g_vh + (size_t)idx * 2) =
            make_uint2(*(unsigned int*)&p0, *(unsigned int*)&p1);
        return;
    }
    __shared__ float Ws[H_ * 64];
    __shared__ float Xs[32 * H_];
    const bool isq = (bx < 32);
    const float* X; const float* W; int r0;
    if (isq) { X = q; W = Wq; r0 = bx * 32; }
    else     { X = k; W = Wk; r0 = (bx - 32) * 32; }

    #pragma unroll
    for (int u = 0; u < 8; ++u) {
        int p = u * 256 + t;
        int kk = p >> 4, c4 = p & 15;
        *(float4*)(Ws + kk * 64 + c4 * 4) = *(const float4*)(W + kk * H_ + ch * 64 + c4 * 4);
    }
    #pragma unroll
    for (int u = 0; u < 4; ++u) {
        int idx = u * 256 + t;
        int r = idx >> 5, c = idx & 31;
        *(float4*)(Xs + r * H_ + c * 4) = *(const float4*)(X + (size_t)(r0 + r) * H_ + c * 4);
    }
    __syncthreads();

    const int rr = t >> 4;               // [0,16): 2 rows
    const int cc = t & 15;               // [0,16): 4 cols
    float acc[2][4] = {};
    #pragma unroll 4
    for (int kk = 0; kk < H_; ++kk) {
        float4 w4 = *(const float4*)(Ws + kk * 64 + cc * 4);
        float x0 = Xs[(rr * 2) * H_ + kk];
        float x1 = Xs[(rr * 2 + 1) * H_ + kk];
        acc[0][0] = fmaf(x0, w4.x, acc[0][0]); acc[0][1] = fmaf(x0, w4.y, acc[0][1]);
        acc[0][2] = fmaf(x0, w4.z, acc[0][2]); acc[0][3] = fmaf(x0, w4.w, acc[0][3]);
        acc[1][0] = fmaf(x1, w4.x, acc[1][0]); acc[1][1] = fmaf(x1, w4.y, acc[1][1]);
        acc[1][2] = fmaf(x1, w4.z, acc[1][2]); acc[1][3] = fmaf(x1, w4.w, acc[1][3]);
    }
    if (isq) {
        #pragma unroll
        for (int i = 0; i < 2; ++i) {
            float4 o;
            o.x = __builtin_amdgcn_exp2f(acc[i][0] * C2LOG2E);
            o.y = __builtin_amdgcn_exp2f(acc[i][1] * C2LOG2E);
            o.z = __builtin_amdgcn_exp2f(acc[i][2] * C2LOG2E);
            o.w = __builtin_amdgcn_exp2f(acc[i][3] * C2LOG2E);
            *(float4*)(g_eq + (size_t)(r0 + rr * 2 + i) * H_ + ch * 64 + cc * 4) = o;
        }
    } else {
        const int b  = r0 >> 10;
        const int s0 = (r0 & 1023) + rr * 2;
        const int h4 = ch * 16 + cc;
        uint4 pk;
        #pragma unroll
        for (int j = 0; j < 4; ++j) {
            float e0 = __builtin_amdgcn_exp2f(acc[0][j] * C2LOG2E);   // s even
            float e1 = __builtin_amdgcn_exp2f(acc[1][j] * C2LOG2E);   // s odd
            __half2 p = __floats2half2_rn(e0, e1);
            ((unsigned int*)&pk)[j] = *(unsigned int*)&p;
        }
        g_ekT4[((size_t)b * (H_ / 4) + h4) * (LK_ / 2) + (s0 >> 1)] = pk;
    }
}

// Fused scores + softmax + PV, one row per block: 1024 x 512 (32 waves/CU).
// R19 change: 8-deep batched loads (static-index register arrays, fully
// unrolled) in phase 1 and PV -- raises per-thread loads-in-flight 2 -> 8
// (~8KB/CU in flight) to cover L2 latency at BW share. Math order unchanged.
__global__ __launch_bounds__(512, 8) void fused_attn(const int* __restrict__ valid_lens,
                                                     const float* __restrict__ w_v,
                                                     float* __restrict__ out) {
    __shared__ float sc[LK_];
    __shared__ float sred[8];
    __shared__ float rinv_s;
    __shared__ float part[16][H_];
    const int t = threadIdx.x;
    const int lane = t & 63, wid = t >> 6;
    const int b = blockIdx.x >> 7, l = blockIdx.x & 127;
    int valid = valid_lens[b];
    valid = min(max(valid, 0), LK_);

    // ---- Phase 1: scores -> weights (exp folded), masked partial sums ----
    const int s0 = 2 * t;
    float e0 = 0.0f, e1 = 0.0f;
    if (valid == 0) {
        for (int i = t; i < LK_; i += 512) sc[i] = 1.0f;
    } else if (s0 < valid) {
        const float* __restrict__ q0 = g_eq + (size_t)(b * LQ_ + l) * H_;
        const uint4* __restrict__ ek = g_ekT4 + (size_t)b * (H_ / 4) * (LK_ / 2) + t;
        float a0 = 0.0f, a1 = 0.0f;
        #pragma unroll
        for (int hb = 0; hb < 4; ++hb) {             // 4 batches x 8 h4
            uint4 r[8];
            #pragma unroll
            for (int i = 0; i < 8; ++i)
                r[i] = ek[(size_t)(hb * 8 + i) * (LK_ / 2)];
            #pragma unroll
            for (int i = 0; i < 8; ++i) {
                #pragma unroll
                for (int j = 0; j < 4; ++j) {
                    unsigned int uj = ((const unsigned int*)&r[i])[j];
                    float2 ef = __half22float2(*(const __half2*)&uj);
                    const int h = (hb * 8 + i) * 4 + j;
                    const float qh = q0[h], wh = w_v[h];
                    a0 = fmaf(wh, __builtin_amdgcn_rcpf(fmaf(qh, ef.x, 1.0f)), a0);
                    a1 = fmaf(wh, __builtin_amdgcn_rcpf(fmaf(qh, ef.y, 1.0f)), a1);
                }
            }
        }
        e0 = __builtin_amdgcn_exp2f(a0 * (-2.0f * 1.44269504f));
        float e1f = __builtin_amdgcn_exp2f(a1 * (-2.0f * 1.44269504f));
        *(float2*)(sc + s0) = make_float2(e0, e1f);
        e1 = (s0 + 1 < valid) ? e1f : 0.0f;
    }
    // ---- Phase 2: sum reduce over in-register weights ----
    float ps = e0 + e1;
    #pragma unroll
    for (int kk = 32; kk; kk >>= 1) ps += __shfl_xor(ps, kk, 64);
    if (lane == 0) sred[wid] = ps;
    __syncthreads();
    if (t == 0) {
        float s8 = ((sred[0] + sred[1]) + (sred[2] + sred[3]))
                 + ((sred[4] + sred[5]) + (sred[6] + sred[7]));
        rinv_s = (valid == 0) ? (1.0f / 1024.0f) : (1.0f / s8);
    }
    __syncthreads();
    const float rinv = rinv_s;
    const int n = (valid == 0) ? LK_ : valid;

    // ---- Phase 3: PV. uint2 = 4 v per lane; 16-way s-split, 8-deep batches ----
    const int c = t >> 5;                // s-chunk [0,16)
    const int v4 = t & 31;               // 4-v group
    const uint2* vb = (const uint2*)g_vh + (size_t)b * LK_ * (H_ / 4) + v4;
    float ax = 0.0f, ay = 0.0f, az = 0.0f, aw = 0.0f;
    int s = c;
    for (; s + 16 * 7 < n; s += 16 * 8) {
        uint2 r[8];
        #pragma unroll
        for (int i = 0; i < 8; ++i)
            r[i] = vb[(size_t)(s + 16 * i) * (H_ / 4)];
        #pragma unroll
        for (int i = 0; i < 8; ++i) {
            float2 v01 = __half22float2(*(const __half2*)&r[i].x);
            float2 v23 = __half22float2(*(const __half2*)&r[i].y);
            float w = sc[s + 16 * i];
            ax = fmaf(w, v01.x, ax); ay = fmaf(w, v01.y, ay);
            az = fmaf(w, v23.x, az); aw = fmaf(w, v23.y, aw);
        }
    }
    for (; s < n; s += 16) {
        uint2 u = vb[(size_t)s * (H_ / 4)];
        float2 v01 = __half22float2(*(const __half2*)&u.x);
        float2 v23 = __half22float2(*(const __half2*)&u.y);
        float w = sc[s];
        ax = fmaf(w, v01.x, ax); ay = fmaf(w, v01.y, ay);
        az = fmaf(w, v23.x, az); aw = fmaf(w, v23.y, aw);
    }
    *(float4*)(&part[c][4 * v4]) = make_float4(ax, ay, az, aw);
    __syncthreads();
    if (t < H_) {
        float o = 0.0f;
        #pragma unroll
        for (int cc2 = 0; cc2 < 16; ++cc2) o += part[cc2][t];
        out[(b * LQ_ + l) * H_ + t] = o * rinv;
    }
}

extern "C" void kernel_launch(void* const* d_in, const int* in_sizes, int n_in,
                              void* d_out, int out_size, void* d_ws, size_t ws_size,
                              hipStream_t stream) {
    const float* queries    = (const float*)d_in[0];
    const float* keys       = (const float*)d_in[1];
    const float* values     = (const float*)d_in[2];
    const int*   valid_lens = (const int*)d_in[3];
    const float* W_q        = (const float*)d_in[4];
    const float* W_k        = (const float*)d_in[5];
    const float* w_v        = (const float*)d_in[6];
    float* out = (float*)d_out;
    (void)d_ws; (void)ws_size; (void)in_sizes; (void)n_in; (void)out_size;

    proj_conv <<<dim3(800, 2), 256, 0, stream>>>(queries, keys, W_q, W_k, values);
    fused_attn<<<1024, 512, 0, stream>>>(valid_lens, w_v, out);
}